// Round 3
// baseline (2356.413 us; speedup 1.0000x reference)
//
#include <hip/hip_runtime.h>
#include <hip/hip_bf16.h>

#define NS 512
#define NB 256
#define NA 16
#define NR_ 256

typedef short s16x8 __attribute__((ext_vector_type(8)));
typedef float f32x4 __attribute__((ext_vector_type(4)));
typedef unsigned u32x4 __attribute__((ext_vector_type(4)));

union BU { uint4 u4; unsigned short us[8]; s16x8 v; unsigned long long ull[2]; };

__device__ __forceinline__ float bf2f(unsigned short h){
  unsigned u = ((unsigned)h) << 16;
  return __builtin_bit_cast(float, u);
}
__device__ __forceinline__ unsigned short f2bf(float f){
  unsigned u = __builtin_bit_cast(unsigned, f);
  u += 0x7fffu + ((u >> 16) & 1u);
  return (unsigned short)(u >> 16);
}
__device__ __forceinline__ float fsig(float x){ return 1.f/(1.f+__expf(-x)); }
__device__ __forceinline__ float ftanh_(float x){ float e=__expf(2.f*x); return 1.f - 2.f/(e+1.f); }

// ---- detect done_flags dtype: u8-bool vs int32 (hdr[0]=1 -> byte format) ----
__global__ void k_detect(const unsigned* __restrict__ done, unsigned* __restrict__ hdr){
  unsigned any = 0;
  for (int i = threadIdx.x; i < 32768; i += 256) any |= (done[i] > 1u) ? 1u : 0u;
  if (__ballot(any)) { if ((threadIdx.x & 63) == 0) atomicOr(hdr, 1u); }
}

__global__ void k_norm(const unsigned char* __restrict__ d8, const int* __restrict__ d32,
                       const unsigned* __restrict__ hdr, unsigned char* __restrict__ dm){
  int i = blockIdx.x*256 + threadIdx.x;
  bool u8 = (hdr[0] & 1u) != 0;
  unsigned char v;
  if (u8) v = (d8[i] != 0) ? 1 : 0; else v = (d32[i] != 0) ? 1 : 0;
  dm[i] = v;
}

// ---- w_ih -> bf16 padded (1024 x 96), bsum = b_ih + b_hh ----
__global__ void k_wbprep(const float* __restrict__ w_ih, const float* __restrict__ b_ih,
                         const float* __restrict__ b_hh, unsigned short* __restrict__ wb,
                         float* __restrict__ bsum){
  const int g = blockIdx.x*256 + threadIdx.x;
  bsum[g] = b_ih[g] + b_hh[g];
  const float* src = w_ih + (size_t)g*81;
  unsigned short* dst = wb + (size_t)g*96;
  for (int k=0;k<81;k++) dst[k]=f2bf(src[k]);
  for (int k=81;k<96;k++) dst[k]=0;
}

// ---- activations: act[r, 0:96] = [fc(x) | reward | onehot | pad] bf16 ----
__global__ void k_act(const float* __restrict__ input, const float* __restrict__ reward,
                      const int* __restrict__ lastact, const float* __restrict__ fc_w,
                      const float* __restrict__ fc_b, unsigned short* __restrict__ act, int n0){
  __shared__ float wf[1024];
  __shared__ float bfc[64];
  const int tid = threadIdx.x;
  for (int i=tid;i<1024;i+=256) wf[i]=fc_w[i];
  if (tid<64) bfc[tid]=fc_b[tid];
  __syncthreads();
  const int r = blockIdx.x*256 + tid;
  const int n = n0 + r;
  float in[16];
  const float4* ip = (const float4*)(input + (size_t)n*16);
  #pragma unroll
  for (int i=0;i<4;i++){ float4 v=ip[i]; in[4*i]=v.x; in[4*i+1]=v.y; in[4*i+2]=v.z; in[4*i+3]=v.w; }
  unsigned short o[96];
  const float4* wf4=(const float4*)wf;
  #pragma unroll
  for (int q=0;q<64;q++){
    float a=bfc[q];
    #pragma unroll
    for (int k4=0;k4<4;k4++){
      float4 wv=wf4[q*4+k4];
      a += in[4*k4]*wv.x + in[4*k4+1]*wv.y + in[4*k4+2]*wv.z + in[4*k4+3]*wv.w;
    }
    o[q]=f2bf(a);
  }
  o[64]=f2bf(reward[n]);
  const int la = lastact[n];
  #pragma unroll
  for (int k=0;k<16;k++) o[65+k] = (k==la) ? (unsigned short)0x3F80 : (unsigned short)0;
  #pragma unroll
  for (int k=81;k<96;k++) o[k]=0;
  uint4* dst=(uint4*)(act + (size_t)r*96);
  #pragma unroll
  for (int i=0;i<12;i++){
    BU b;
    #pragma unroll
    for (int jj=0;jj<8;jj++) b.us[jj]=o[i*8+jj];
    dst[i]=b.u4;
  }
}

// ---- Xg GEMM: xg[M,1024] = act[M,96] @ wb[1024,96]^T + bsum, bf16 out ----
__launch_bounds__(256,1) __global__ void k_gemm(
    const unsigned short* __restrict__ act, const unsigned short* __restrict__ wb,
    const float* __restrict__ bsum, unsigned short* __restrict__ xg, int mtiles){
  __shared__ __align__(16) unsigned short lA[128*104];
  __shared__ __align__(16) unsigned short lB[128*104];
  const int bm = blockIdx.x % mtiles;
  const int bn = blockIdx.x / mtiles;
  const int tid = threadIdx.x;
  {
    const int r = tid >> 1, sg = tid & 1;
    const uint4* sa = (const uint4*)(act + (size_t)(bm*128 + r)*96 + sg*48);
    const uint4* sb = (const uint4*)(wb  + (size_t)(bn*128 + r)*96 + sg*48);
    uint4* da = (uint4*)&lA[r*104 + sg*48];
    uint4* db = (uint4*)&lB[r*104 + sg*48];
    #pragma unroll
    for (int i=0;i<6;i++){ da[i]=sa[i]; db[i]=sb[i]; }
  }
  __syncthreads();
  const int wid = tid >> 6, lane = tid & 63;
  const int wm = wid >> 1, wn = wid & 1;
  const int lr = lane & 15, lp = lane >> 4;
  f32x4 acc[4][4] = {};
  #pragma unroll
  for (int kt=0;kt<3;kt++){
    s16x8 af[4], bf[4];
    #pragma unroll
    for (int mi=0;mi<4;mi++)
      af[mi] = *(const s16x8*)&lA[(wm*64 + mi*16 + lr)*104 + kt*32 + lp*8];
    #pragma unroll
    for (int ni=0;ni<4;ni++)
      bf[ni] = *(const s16x8*)&lB[(wn*64 + ni*16 + lr)*104 + kt*32 + lp*8];
    #pragma unroll
    for (int mi=0;mi<4;mi++){
      #pragma unroll
      for (int ni=0;ni<4;ni++)
        acc[mi][ni] = __builtin_amdgcn_mfma_f32_16x16x32_bf16(af[mi], bf[ni], acc[mi][ni], 0,0,0);
    }
  }
  #pragma unroll
  for (int ni=0;ni<4;ni++){
    const int col = bn*128 + wn*64 + ni*16 + lr;
    const float bias = bsum[col];
    #pragma unroll
    for (int mi=0;mi<4;mi++){
      const int row = bm*128 + wm*64 + mi*16 + lp*4;
      #pragma unroll
      for (int rr=0;rr<4;rr++)
        xg[((size_t)(row+rr)<<10) + col] = f2bf(acc[mi][ni][rr] + bias);
    }
  }
}

// ---- persistent LSTM core (R3): zero-barrier, flag-in-data LL16 packets ----
// 64 WGs = 16 batch-groups x 4 r-slices. Weights register-resident (no LDS).
// Packet: 16B = {2x bf16 h, u32 tag, 2x bf16 h, u32 tag}; tag = global step.
// Stores/loads via sc0 sc1 (coherence point); 8B halves self-validating.
__launch_bounds__(256,1) __global__ void k_main(
    const float* __restrict__ hidden, const unsigned short* __restrict__ xg,
    const unsigned char* __restrict__ dm, const float* __restrict__ w_hh,
    u32x4* __restrict__ pk, float* __restrict__ cstate, int t0, int CH, int CHP){
  const int tid = threadIdx.x;
  const int gb = blockIdx.x >> 2;   // batch group 0..15
  const int j  = blockIdx.x & 3;    // r-slice 0..3
  const int lane = tid & 63, w = tid >> 6;
  const int lr = lane & 15, lp = lane >> 4;
  const int bglob = (gb << 4) + lr;                  // batch row
  const int roff = (j << 6) + (w << 4) + (lp << 2);  // r base within 256

  // register-resident bf16 weight fragments: wf_[gate][kt], 128 VGPRs
  s16x8 wf_[4][8];
  #pragma unroll
  for (int g=0; g<4; ++g){
    #pragma unroll
    for (int kt=0; kt<8; ++kt){
      const float* src = w_hh + (size_t)((g<<8) + (j<<6) + (w<<4) + lr)*256 + (kt<<5) + (lp<<3);
      float4 fa = *(const float4*)src;
      float4 fb = *(const float4*)(src+4);
      BU u;
      u.us[0]=f2bf(fa.x); u.us[1]=f2bf(fa.y); u.us[2]=f2bf(fa.z); u.us[3]=f2bf(fa.w);
      u.us[4]=f2bf(fb.x); u.us[5]=f2bf(fb.y); u.us[6]=f2bf(fb.z); u.us[7]=f2bf(fb.w);
      wf_[g][kt] = u.v;
    }
  }
  float ca[4];
  {
    const float* csrc = (t0 == 0) ? (hidden + 65536) : cstate;
    float4 cv = *(const float4*)(csrc + (size_t)bglob*256 + roff);
    ca[0]=cv.x; ca[1]=cv.y; ca[2]=cv.z; ca[3]=cv.w;
  }

  for (int s = 0; s < CH; ++s){
    const int t = t0 + s;
    const bool dn = dm[t*NB + bglob] != 0;
    const unsigned short* xrow = xg + ((size_t)(s*NB + bglob) << 10) + roff;
    ushort4 xv0 = *(const ushort4*)(xrow);
    ushort4 xv1 = *(const ushort4*)(xrow + 256);
    ushort4 xv2 = *(const ushort4*)(xrow + 512);
    ushort4 xv3 = *(const ushort4*)(xrow + 768);

    s16x8 bfr[8];
    if (t == 0){
      const float* hrow = hidden + (size_t)bglob*256;
      #pragma unroll
      for (int kt=0;kt<8;kt++){
        const float4* pp = (const float4*)(hrow + (kt<<5) + (lp<<3));
        float4 a=pp[0], b=pp[1];
        BU u;
        u.us[0]=f2bf(a.x); u.us[1]=f2bf(a.y); u.us[2]=f2bf(a.z); u.us[3]=f2bf(a.w);
        u.us[4]=f2bf(b.x); u.us[5]=f2bf(b.y); u.us[6]=f2bf(b.z); u.us[7]=f2bf(b.w);
        if (dn) u.u4 = make_uint4(0,0,0,0);
        bfr[kt]=u.v;
      }
    } else {
      const u32x4* pb = pk + ((size_t)(t % CHP) << 14) + ((size_t)bglob << 6) + (lp << 1);
      const u32x4 *A0=pb, *A1=pb+8, *A2=pb+16, *A3=pb+24, *A4=pb+32, *A5=pb+40, *A6=pb+48, *A7=pb+56;
      const unsigned tg = (unsigned)t;
      u32x4 P0,P1,P2,P3,P4,P5,P6,P7,P8,P9,P10,P11,P12,P13,P14,P15;
      for(;;){
        asm volatile(
          "global_load_dwordx4 %0, %16, off sc0 sc1\n\t"
          "global_load_dwordx4 %1, %16, off offset:16 sc0 sc1\n\t"
          "global_load_dwordx4 %2, %17, off sc0 sc1\n\t"
          "global_load_dwordx4 %3, %17, off offset:16 sc0 sc1\n\t"
          "global_load_dwordx4 %4, %18, off sc0 sc1\n\t"
          "global_load_dwordx4 %5, %18, off offset:16 sc0 sc1\n\t"
          "global_load_dwordx4 %6, %19, off sc0 sc1\n\t"
          "global_load_dwordx4 %7, %19, off offset:16 sc0 sc1\n\t"
          "global_load_dwordx4 %8, %20, off sc0 sc1\n\t"
          "global_load_dwordx4 %9, %20, off offset:16 sc0 sc1\n\t"
          "global_load_dwordx4 %10, %21, off sc0 sc1\n\t"
          "global_load_dwordx4 %11, %21, off offset:16 sc0 sc1\n\t"
          "global_load_dwordx4 %12, %22, off sc0 sc1\n\t"
          "global_load_dwordx4 %13, %22, off offset:16 sc0 sc1\n\t"
          "global_load_dwordx4 %14, %23, off sc0 sc1\n\t"
          "global_load_dwordx4 %15, %23, off offset:16 sc0 sc1\n\t"
          "s_waitcnt vmcnt(0)"
          : "=&v"(P0),"=&v"(P1),"=&v"(P2),"=&v"(P3),
            "=&v"(P4),"=&v"(P5),"=&v"(P6),"=&v"(P7),
            "=&v"(P8),"=&v"(P9),"=&v"(P10),"=&v"(P11),
            "=&v"(P12),"=&v"(P13),"=&v"(P14),"=&v"(P15)
          : "v"(A0),"v"(A1),"v"(A2),"v"(A3),"v"(A4),"v"(A5),"v"(A6),"v"(A7)
          : "memory");
        unsigned m =
          (P0[1]^tg)|(P0[3]^tg)|(P1[1]^tg)|(P1[3]^tg)|
          (P2[1]^tg)|(P2[3]^tg)|(P3[1]^tg)|(P3[3]^tg)|
          (P4[1]^tg)|(P4[3]^tg)|(P5[1]^tg)|(P5[3]^tg)|
          (P6[1]^tg)|(P6[3]^tg)|(P7[1]^tg)|(P7[3]^tg)|
          (P8[1]^tg)|(P8[3]^tg)|(P9[1]^tg)|(P9[3]^tg)|
          (P10[1]^tg)|(P10[3]^tg)|(P11[1]^tg)|(P11[3]^tg)|
          (P12[1]^tg)|(P12[3]^tg)|(P13[1]^tg)|(P13[3]^tg)|
          (P14[1]^tg)|(P14[3]^tg)|(P15[1]^tg)|(P15[3]^tg);
        if (m == 0) break;
      }
      BU u;
      u.u4 = make_uint4(P0[0],P0[2],P1[0],P1[2]);   if (dn) u.u4=make_uint4(0,0,0,0); bfr[0]=u.v;
      u.u4 = make_uint4(P2[0],P2[2],P3[0],P3[2]);   if (dn) u.u4=make_uint4(0,0,0,0); bfr[1]=u.v;
      u.u4 = make_uint4(P4[0],P4[2],P5[0],P5[2]);   if (dn) u.u4=make_uint4(0,0,0,0); bfr[2]=u.v;
      u.u4 = make_uint4(P6[0],P6[2],P7[0],P7[2]);   if (dn) u.u4=make_uint4(0,0,0,0); bfr[3]=u.v;
      u.u4 = make_uint4(P8[0],P8[2],P9[0],P9[2]);   if (dn) u.u4=make_uint4(0,0,0,0); bfr[4]=u.v;
      u.u4 = make_uint4(P10[0],P10[2],P11[0],P11[2]); if (dn) u.u4=make_uint4(0,0,0,0); bfr[5]=u.v;
      u.u4 = make_uint4(P12[0],P12[2],P13[0],P13[2]); if (dn) u.u4=make_uint4(0,0,0,0); bfr[6]=u.v;
      u.u4 = make_uint4(P14[0],P14[2],P15[0],P15[2]); if (dn) u.u4=make_uint4(0,0,0,0); bfr[7]=u.v;
    }

    f32x4 a0, a1, a2, a3;
    a0[0]=bf2f(xv0.x); a0[1]=bf2f(xv0.y); a0[2]=bf2f(xv0.z); a0[3]=bf2f(xv0.w);
    a1[0]=bf2f(xv1.x); a1[1]=bf2f(xv1.y); a1[2]=bf2f(xv1.z); a1[3]=bf2f(xv1.w);
    a2[0]=bf2f(xv2.x); a2[1]=bf2f(xv2.y); a2[2]=bf2f(xv2.z); a2[3]=bf2f(xv2.w);
    a3[0]=bf2f(xv3.x); a3[1]=bf2f(xv3.y); a3[2]=bf2f(xv3.z); a3[3]=bf2f(xv3.w);

    #pragma unroll
    for (int kt=0;kt<8;kt++){
      a0 = __builtin_amdgcn_mfma_f32_16x16x32_bf16(wf_[0][kt], bfr[kt], a0, 0,0,0);
      a1 = __builtin_amdgcn_mfma_f32_16x16x32_bf16(wf_[1][kt], bfr[kt], a1, 0,0,0);
      a2 = __builtin_amdgcn_mfma_f32_16x16x32_bf16(wf_[2][kt], bfr[kt], a2, 0,0,0);
      a3 = __builtin_amdgcn_mfma_f32_16x16x32_bf16(wf_[3][kt], bfr[kt], a3, 0,0,0);
    }

    unsigned short hu[4];
    #pragma unroll
    for (int rr=0;rr<4;rr++){
      float cp = dn ? 0.f : ca[rr];
      float ii=fsig(a0[rr]), ff=fsig(a1[rr]), gg=ftanh_(a2[rr]), oo=fsig(a3[rr]);
      float cn = ff*cp + ii*gg;
      ca[rr] = cn;
      hu[rr] = f2bf(oo*ftanh_(cn));
    }
    u32x4 op = { (unsigned)hu[0] | ((unsigned)hu[1]<<16), (unsigned)(t+1),
                 (unsigned)hu[2] | ((unsigned)hu[3]<<16), (unsigned)(t+1) };
    u32x4* dst = pk + ((size_t)((t+1) % CHP) << 14) + ((size_t)bglob << 6) + (roff >> 2);
    asm volatile("global_store_dwordx4 %0, %1, off sc0 sc1" :: "v"(dst), "v"(op) : "memory");
  }
  *(float4*)(cstate + (size_t)bglob*256 + roff) = make_float4(ca[0],ca[1],ca[2],ca[3]);
}

// ---- heads: logits = h@actor_w.T + b ; values = h@critic_w.T + b ----
__launch_bounds__(64,1) __global__ void k_proj(
    const uint4* __restrict__ pk, const float* __restrict__ actor_w,
    const float* __restrict__ actor_b, const float* __restrict__ critic_w,
    const float* __restrict__ critic_b, float* __restrict__ outL,
    float* __restrict__ outV, int t0, int CHP){
  const int lane = threadIdx.x;
  const int m0 = blockIdx.x * 64;          // row within chunk (row = s*256 + batch)
  const int sloc = m0 >> 8;
  const int b0 = m0 & 255;
  const uint4* base = pk + ((size_t)((t0 + sloc + 1) % CHP) << 14);
  const int lr = lane & 15, lp = lane >> 4;
  f32x4 acc[4] = {};
  float part[4] = {0.f,0.f,0.f,0.f};
  #pragma unroll
  for (int kt=0;kt<8;kt++){
    BU bw;
    const float4* ap = (const float4*)(actor_w + (size_t)lr*256 + (kt<<5) + (lp<<3));
    float4 w0=ap[0], w1=ap[1];
    bw.us[0]=f2bf(w0.x); bw.us[1]=f2bf(w0.y); bw.us[2]=f2bf(w0.z); bw.us[3]=f2bf(w0.w);
    bw.us[4]=f2bf(w1.x); bw.us[5]=f2bf(w1.y); bw.us[6]=f2bf(w1.z); bw.us[7]=f2bf(w1.w);
    const float4* cp4 = (const float4*)(critic_w + (kt<<5) + (lp<<3));
    float4 cw0=cp4[0], cw1=cp4[1];
    #pragma unroll
    for (int mi=0;mi<4;mi++){
      const int b = b0 + mi*16 + lr;
      const uint4* q = base + ((size_t)b << 6) + (kt<<3) + (lp<<1);
      uint4 q0 = q[0], q1 = q[1];
      BU hv; hv.u4 = make_uint4(q0.x, q0.z, q1.x, q1.z);
      acc[mi] = __builtin_amdgcn_mfma_f32_16x16x32_bf16(hv.v, bw.v, acc[mi], 0,0,0);
      part[mi] += bf2f(hv.us[0])*cw0.x + bf2f(hv.us[1])*cw0.y + bf2f(hv.us[2])*cw0.z + bf2f(hv.us[3])*cw0.w
                + bf2f(hv.us[4])*cw1.x + bf2f(hv.us[5])*cw1.y + bf2f(hv.us[6])*cw1.z + bf2f(hv.us[7])*cw1.w;
    }
  }
  const float ab = actor_b[lr];
  #pragma unroll
  for (int mi=0;mi<4;mi++){
    #pragma unroll
    for (int rr=0;rr<4;rr++)
      outL[(size_t)(m0 + mi*16 + lp*4 + rr)*16 + lr] = acc[mi][rr] + ab;
  }
  const float cb = critic_b[0];
  #pragma unroll
  for (int mi=0;mi<4;mi++){
    float v = part[mi];
    v += __shfl_xor(v, 16, 64);
    v += __shfl_xor(v, 32, 64);
    if (lp == 0) outV[m0 + mi*16 + lr] = v + cb;
  }
}

extern "C" void kernel_launch(void* const* d_in, const int* in_sizes, int n_in,
                              void* d_out, int out_size, void* d_ws, size_t ws_size,
                              hipStream_t stream) {
  (void)in_sizes; (void)n_in; (void)out_size;
  const float* input    = (const float*)d_in[0];
  const int*   lastact  = (const int*)d_in[1];
  const float* reward   = (const float*)d_in[2];
  const void*  done     = d_in[3];
  const float* hidden   = (const float*)d_in[4];
  const float* fc_w     = (const float*)d_in[5];
  const float* fc_b     = (const float*)d_in[6];
  const float* w_ih     = (const float*)d_in[7];
  const float* w_hh     = (const float*)d_in[8];
  const float* b_ih     = (const float*)d_in[9];
  const float* b_hh     = (const float*)d_in[10];
  const float* actor_w  = (const float*)d_in[11];
  const float* actor_b  = (const float*)d_in[12];
  const float* critic_w = (const float*)d_in[13];
  const float* critic_b = (const float*)d_in[14];
  float* outL = (float*)d_out;
  float* outV = outL + (size_t)NS*NA*NB;

  char* p = (char*)d_ws;
  unsigned*       hdr    = (unsigned*)p;              // 256B
  unsigned char*  dmb    = (unsigned char*)(p + 1024);            // 131072
  unsigned short* wb     = (unsigned short*)(p + 132096);         // 196608
  float*          bsum   = (float*)(p + 328704);                  // 4096
  float*          cstate = (float*)(p + 332800);                  // 262144
  const size_t fixed = 594944;
  int CH = 256;
  while (CH > 4){
    size_t need = fixed + (size_t)CH*49152 + (size_t)CH*524288 + ((size_t)CH+1)*262144;
    if (need <= ws_size) break;
    CH >>= 1;
  }
  const int CHP = CH + 1;
  unsigned short* act = (unsigned short*)(p + fixed);
  unsigned short* xg  = (unsigned short*)(p + fixed + (size_t)CH*49152);
  char*           pkb = p + fixed + (size_t)CH*49152 + (size_t)CH*524288;

  hipMemsetAsync(d_ws, 0, 1024, stream);
  hipMemsetAsync(pkb, 0, (size_t)CHP*262144, stream);   // clear packet tags
  hipLaunchKernelGGL(k_detect, dim3(1), dim3(256), 0, stream, (const unsigned*)done, hdr);
  hipLaunchKernelGGL(k_norm, dim3(512), dim3(256), 0, stream,
                     (const unsigned char*)done, (const int*)done, hdr, dmb);
  hipLaunchKernelGGL(k_wbprep, dim3(4), dim3(256), 0, stream, w_ih, b_ih, b_hh, wb, bsum);

  const int NC = NS / CH;
  for (int c = 0; c < NC; ++c){
    const int t0 = c * CH;
    hipLaunchKernelGGL(k_act, dim3(CH), dim3(256), 0, stream,
                       input, reward, lastact, fc_w, fc_b, act, t0*NB);
    hipLaunchKernelGGL(k_gemm, dim3(CH*2*8), dim3(256), 0, stream, act, wb, bsum, xg, CH*2);
    hipLaunchKernelGGL(k_main, dim3(64), dim3(256), 0, stream,
                       hidden, xg, dmb, w_hh, (u32x4*)pkb, cstate, t0, CH, CHP);
    hipLaunchKernelGGL(k_proj, dim3(CH*4), dim3(64), 0, stream,
                       (const uint4*)pkb, actor_w, actor_b, critic_w, critic_b,
                       outL + (size_t)t0*NB*NA, outV + (size_t)t0*NB, t0, CHP);
  }
}